// Round 1
// baseline (245.101 us; speedup 1.0000x reference)
//
#include <hip/hip_runtime.h>
#include <hip/hip_bf16.h>

#define D_DIM 128
#define MT 64            // node rows per block
#define LDSS 136         // 128 + 8 bf16 pad: +4-bank rotation/row, keeps 16B alignment

typedef __attribute__((ext_vector_type(8))) short bf16x8;
typedef __attribute__((ext_vector_type(4))) float f32x4;

__device__ __forceinline__ unsigned short f2bf(float f) {
    return __builtin_bit_cast(unsigned short, __float2bfloat16(f));
}

__global__ void prep_weights(const float* __restrict__ w1,
                             const float* __restrict__ w2,
                             unsigned short* __restrict__ w1b,
                             unsigned short* __restrict__ w2b) {
    int t = blockIdx.x * blockDim.x + threadIdx.x;
    if (t < D_DIM * D_DIM) {
        w1b[t] = f2bf(w1[t]);
        w2b[t] = f2bf(w2[t]);
    }
}

__global__ __launch_bounds__(256, 4)
void ctx_encoder(const int* __restrict__ nodes,
                 const float* __restrict__ c2e,
                 const unsigned short* __restrict__ w1b,
                 const float* __restrict__ b1,
                 const unsigned short* __restrict__ w2b,
                 const float* __restrict__ b2,
                 float* __restrict__ out,
                 int N) {
    __shared__ unsigned short sA[MT][LDSS];
    __shared__ unsigned short sH[MT][LDSS];

    const int t = threadIdx.x;
    const int nodeBase = blockIdx.x * MT;

    // ---- gather 64 embedding rows, fp32 -> bf16, stage in LDS ----
    {
        const int chunk = t & 31;     // float4 chunk within a 128-float row
        int row = t >> 5;             // starting row; +8 per iteration
        #pragma unroll
        for (int i = 0; i < 8; ++i, row += 8) {
            int gr = nodeBase + row;
            gr = gr < N ? gr : N - 1;               // clamp (N%64==0 normally)
            const int nd = nodes[gr];
            const float4 v = ((const float4*)c2e)[(size_t)nd * 32 + chunk];
            ushort4 b;
            b.x = f2bf(v.x); b.y = f2bf(v.y); b.z = f2bf(v.z); b.w = f2bf(v.w);
            *(ushort4*)&sA[row][chunk * 4] = b;     // 8B, bank-balanced
        }
    }
    __syncthreads();

    const int lane = t & 63;
    const int wave = t >> 6;
    const int m0   = wave * 16;     // each wave owns a 16-row tile
    const int cl   = lane & 15;
    const int quad = lane >> 4;
    const int rb   = quad * 4;      // C/D row base: row = quad*4 + reg

    // ---- layer 1: h = relu(ce @ W1^T + b1) ----
    bf16x8 aF[4];
    #pragma unroll
    for (int ks = 0; ks < 4; ++ks)
        aF[ks] = *(const bf16x8*)&sA[m0 + cl][ks * 32 + quad * 8];

    #pragma unroll
    for (int ct = 0; ct < 8; ++ct) {
        f32x4 acc = {0.f, 0.f, 0.f, 0.f};
        #pragma unroll
        for (int ks = 0; ks < 4; ++ks) {
            // W row-major [i][k] is exactly the B^T fragment layout
            bf16x8 bF = *(const bf16x8*)&w1b[(ct * 16 + cl) * D_DIM + ks * 32 + quad * 8];
            acc = __builtin_amdgcn_mfma_f32_16x16x32_bf16(aF[ks], bF, acc, 0, 0, 0);
        }
        const int j = ct * 16 + cl;
        const float bias = b1[j];
        #pragma unroll
        for (int r = 0; r < 4; ++r) {
            float h = acc[r] + bias;
            h = h > 0.f ? h : 0.f;
            sH[m0 + rb + r][j] = f2bf(h);
        }
    }
    __syncthreads();

    // ---- layer 2: out = relu(h @ W2^T + b2) ----
    #pragma unroll
    for (int ks = 0; ks < 4; ++ks)
        aF[ks] = *(const bf16x8*)&sH[m0 + cl][ks * 32 + quad * 8];

    #pragma unroll
    for (int ct = 0; ct < 8; ++ct) {
        f32x4 acc = {0.f, 0.f, 0.f, 0.f};
        #pragma unroll
        for (int ks = 0; ks < 4; ++ks) {
            bf16x8 bF = *(const bf16x8*)&w2b[(ct * 16 + cl) * D_DIM + ks * 32 + quad * 8];
            acc = __builtin_amdgcn_mfma_f32_16x16x32_bf16(aF[ks], bF, acc, 0, 0, 0);
        }
        const int j = ct * 16 + cl;
        const float bias = b2[j];
        #pragma unroll
        for (int r = 0; r < 4; ++r) {
            float o = acc[r] + bias;
            o = o > 0.f ? o : 0.f;
            const int grow = nodeBase + m0 + rb + r;
            if (grow < N)
                out[(size_t)grow * D_DIM + j] = o;
        }
    }
}

extern "C" void kernel_launch(void* const* d_in, const int* in_sizes, int n_in,
                              void* d_out, int out_size, void* d_ws, size_t ws_size,
                              hipStream_t stream) {
    const int*   nodes = (const int*)d_in[0];
    const float* c2e   = (const float*)d_in[1];
    const float* w1    = (const float*)d_in[2];
    const float* b1    = (const float*)d_in[3];
    const float* w2    = (const float*)d_in[4];
    const float* b2    = (const float*)d_in[5];
    float* out = (float*)d_out;
    const int N = in_sizes[0];

    unsigned short* w1b = (unsigned short*)d_ws;
    unsigned short* w2b = w1b + D_DIM * D_DIM;

    // ws is re-poisoned before every call -> must reconvert weights each launch
    prep_weights<<<dim3((D_DIM * D_DIM + 255) / 256), dim3(256), 0, stream>>>(w1, w2, w1b, w2b);

    const int grid = (N + MT - 1) / MT;
    ctx_encoder<<<dim3(grid), dim3(256), 0, stream>>>(nodes, c2e, w1b, b1, w2b, b2, out, N);
}